// Round 9
// baseline (270.018 us; speedup 1.0000x reference)
//
#include <hip/hip_runtime.h>

#define B_    512
#define IN_   256
#define H_    512
#define OUT_  64
#define NDEATH (B_ - 1)
#define NSORT  512          // NDEATH padded to pow2 for bitonic sort / bsearch
#define RTOL_ 1e-6
#define ATOL_ 1e-8
#define NG    512           // grid: 2 blocks/CU
#define NTILE 16            // 512 rows / 32-row tiles (pdist)
#define NTP   136           // NTILE*(NTILE+1)/2 tile-pairs
#define RSTR  65            // padded LDS row stride
#define YSZ   (B_ * OUT_)   // 32768 elems per yv partial

typedef __attribute__((ext_vector_type(4))) double d4_t;

// ---------------------------------------------------------------------------
// software grid barrier (single-use counter): release add, relaxed spin,
// one acquire on exit. (R6-verified)
// ---------------------------------------------------------------------------
__device__ __forceinline__ void gbar(unsigned* cnt, unsigned nb, bool wait) {
    __syncthreads();
    if (threadIdx.x == 0) {
        __hip_atomic_fetch_add(cnt, 1u, __ATOMIC_RELEASE,
                               __HIP_MEMORY_SCOPE_AGENT);
        if (wait) {
            while (__hip_atomic_load(cnt, __ATOMIC_RELAXED,
                                     __HIP_MEMORY_SCOPE_AGENT) < nb)
                __builtin_amdgcn_s_sleep(2);
            (void)__hip_atomic_load(cnt, __ATOMIC_ACQUIRE,
                                    __HIP_MEMORY_SCOPE_AGENT);
        }
    }
    __syncthreads();
}

// ---------------------------------------------------------------------------
// per-block: bitonic-sort deaths into LDS, emit sorted tolerance windows.
// 256 threads, 512 elements. (verified R5-R7)
// ---------------------------------------------------------------------------
__device__ void sort_windows(const float* __restrict__ deaths,
                             double* sd, double* slo, double* shi, int t) {
    int i1 = t + 256;
    sd[t]  = (t  < NDEATH) ? (double)deaths[t]  : 1e300;
    sd[i1] = (i1 < NDEATH) ? (double)deaths[i1] : 1e300;
    __syncthreads();
    for (int k = 2; k <= NSORT; k <<= 1) {
        for (int j = k >> 1; j > 0; j >>= 1) {
            int l = ((t & ~(j - 1)) << 1) | (t & (j - 1));   // pair (l, l+j)
            int p = l + j;
            bool up = ((l & k) == 0);
            double a = sd[l], b = sd[p];
            if ((a > b) == up) { sd[l] = b; sd[p] = a; }
            __syncthreads();
        }
    }
    for (int i = t; i < NSORT; i += 256) {
        double d = sd[i];
        double w = ATOL_ + RTOL_ * fabs(d);
        slo[i] = d - w;
        shi[i] = d + w;
    }
    __syncthreads();
}

// ---------------------------------------------------------------------------
// K-split f64 MFMA GEMM: RAW partial C_tile = A[rows, kOff:kOff+Ksub] @
// W[kOff:kOff+Ksub, cols] (consumer combines bias/relu).
// COMBINE: A element = relu(A0[i]+A1[i]+bp[k]) built during staging.
// 32x32 tile, 4 waves x one v_mfma_f64_16x16x4_f64, Kt=16, double-buffered.
// ---------------------------------------------------------------------------
template <typename TIN, bool COMBINE>
__device__ void gemm_split(const TIN* __restrict__ A0, const TIN* __restrict__ A1,
                           const float* __restrict__ bp,
                           const float* __restrict__ W, double* __restrict__ C,
                           int N, int lda, int kOff, int Ksub, int tile, int t,
                           double (&As)[2][16][33], double (&Ws)[2][16][33]) {
    const int lane = t & 63;
    const int wave = t >> 6;
    const int wm   = wave & 1, wn = wave >> 1;
    const int nbx  = N >> 5;
    const int row0 = (tile / nbx) << 5;
    const int col0 = (tile % nbx) << 5;

    const int amm0 = t >> 4, akk = t & 15;
    const int amm1 = amm0 + 16;
    const int wkk0 = t >> 5, wnn = t & 31;
    const int wkk1 = wkk0 + 8;
    const int nkt  = Ksub >> 4;

    TIN   a00, a01, a10 = TIN(0), a11 = TIN(0);
    float w0, w1, pb = 0.f;

    auto load_kt = [&](int k0) {
        size_t i0 = (size_t)(row0 + amm0) * lda + kOff + k0 + akk;
        size_t i1 = (size_t)(row0 + amm1) * lda + kOff + k0 + akk;
        a00 = A0[i0];  a01 = A0[i1];
        if (COMBINE) { a10 = A1[i0];  a11 = A1[i1];  pb = bp[kOff + k0 + akk]; }
        w0 = W[(size_t)(kOff + k0 + wkk0) * N + col0 + wnn];
        w1 = W[(size_t)(kOff + k0 + wkk1) * N + col0 + wnn];
    };
    auto stage_kt = [&](int buf) {
        double v0, v1;
        if (COMBINE) {
            double b = (double)pb;
            v0 = (double)a00 + (double)a10 + b;  v0 = v0 > 0.0 ? v0 : 0.0;
            v1 = (double)a01 + (double)a11 + b;  v1 = v1 > 0.0 ? v1 : 0.0;
        } else {
            v0 = (double)a00;  v1 = (double)a01;
        }
        As[buf][akk][amm0] = v0;  As[buf][akk][amm1] = v1;
        Ws[buf][wkk0][wnn] = (double)w0;  Ws[buf][wkk1][wnn] = (double)w1;
    };

    load_kt(0);
    stage_kt(0);
    __syncthreads();

    d4_t c4 = {0.0, 0.0, 0.0, 0.0};
    const int mrow = wm * 16 + (lane & 15);
    const int ncol = wn * 16 + (lane & 15);
    const int kq   = lane >> 4;

    for (int kt = 0; kt < nkt; ++kt) {
        const int cur = kt & 1;
        if (kt + 1 < nkt) load_kt((kt + 1) << 4);
        #pragma unroll
        for (int ks = 0; ks < 4; ++ks) {
            double av = As[cur][ks * 4 + kq][mrow];
            double bv = Ws[cur][ks * 4 + kq][ncol];
            c4 = __builtin_amdgcn_mfma_f64_16x16x4f64(av, bv, c4, 0, 0, 0);
        }
        __syncthreads();
        if (kt + 1 < nkt) stage_kt(cur ^ 1);
        __syncthreads();
    }

    #pragma unroll
    for (int r = 0; r < 4; ++r) {
        int row = row0 + wm * 16 + (lane >> 4) * 4 + r;
        int col = col0 + wn * 16 + (lane & 15);
        C[(size_t)row * N + col] = c4[r];      // raw partial
    }
}

// ---------------------------------------------------------------------------
// combined y value: 2 Wout K-split partials + bout, fixed add order
// (identical expression in pdist staging and mc — deterministic).
// ---------------------------------------------------------------------------
__device__ __forceinline__ double yval(const double* __restrict__ yvp,
                                       const float* __restrict__ bout,
                                       int row, int d) {
    size_t i = (size_t)row * OUT_ + d;
    return yvp[i] + yvp[YSZ + i] + (double)bout[d];
}

// ---------------------------------------------------------------------------
// column c: mean + target-MSE partial + compactness partial -> global slots
// ---------------------------------------------------------------------------
__device__ void mc_dev(const float* __restrict__ target,
                       const double* __restrict__ yvp,
                       const float* __restrict__ bout,
                       double* __restrict__ t_part, double* __restrict__ c_part,
                       int c, int t) {
    const int wave = t >> 6, lane = t & 63;
    double v0 = yval(yvp, bout, t, c);
    double v1 = yval(yvp, bout, t + 256, c);
    double s = v0 + v1;
    for (int off = 32; off; off >>= 1) s += __shfl_down(s, off);
    __shared__ double swm[4];
    __shared__ double smean;
    if (lane == 0) swm[wave] = s;
    __syncthreads();
    if (t == 0) smean = (swm[0] + swm[1] + swm[2] + swm[3]) / (double)B_;
    __syncthreads();
    double m = smean;
    double d0 = (double)target[(size_t)t * OUT_ + c] - v0;
    double d1 = (double)target[(size_t)(t + 256) * OUT_ + c] - v1;
    double t_s = d0 * d0 + d1 * d1;
    double c_s = fabs(v0 - m) + fabs(v1 - m);
    for (int off = 32; off; off >>= 1) {
        t_s += __shfl_down(t_s, off);
        c_s += __shfl_down(c_s, off);
    }
    __shared__ double st[4], sc[4];
    if (lane == 0) { st[wave] = t_s; sc[wave] = c_s; }
    __syncthreads();
    if (t == 0) {
        t_part[c] = st[0] + st[1] + st[2] + st[3];
        c_part[c] = sc[0] + sc[1] + sc[2] + sc[3];
    }
}

// ---------------------------------------------------------------------------
// pdist, LDS-tiled with y-combine at staging. Block handles tile-pair
// (ti<=tj); 32 rows each in LDS. Match via sorted-window bsearch.
// ---------------------------------------------------------------------------
__device__ __forceinline__ double pair_val(const double* __restrict__ ra,
                                           const double* __restrict__ rb,
                                           const double* __restrict__ slo,
                                           const double* __restrict__ shi) {
    double s = 0.0;
    #pragma unroll
    for (int d = 0; d < OUT_; d += 2) {
        double d0 = ra[d]     - rb[d];
        double d1 = ra[d + 1] - rb[d + 1];
        s = fma(d0, d0, s);
        s = fma(d1, d1, s);
    }
    double pd = sqrt(s);
    int pos = 0;
    #pragma unroll
    for (int step = NSORT / 2; step; step >>= 1) {
        if (slo[pos + step - 1] <= pd) pos += step;
    }
    bool m = (pos > 0) && (shi[pos - 1] >= pd);
    return m ? pd : 0.0;
}

__device__ void pdist_dev(const double* __restrict__ yvp,
                          const float* __restrict__ bout,
                          double* __restrict__ hom_part, int pb, int t,
                          double* rowsA, double* rowsB,
                          const double* slo, const double* shi) {
    int ti = 0, rem = pb;
    while (rem >= NTILE - ti) { rem -= NTILE - ti; ++ti; }
    const int tj = ti + rem;

    for (int e = t; e < 32 * OUT_; e += 256) {
        int a = e >> 6, d = e & 63;
        rowsA[a * RSTR + d] = yval(yvp, bout, ti * 32 + a, d);
        rowsB[a * RSTR + d] = yval(yvp, bout, tj * 32 + a, d);
    }
    __syncthreads();

    double local = 0.0;
    #pragma unroll
    for (int q = 0; q < 4; ++q) {
        int p = t + q * 256;
        int a = p >> 5, b = p & 31;
        if (ti == tj && a >= b) continue;
        local += pair_val(rowsA + a * RSTR, rowsB + b * RSTR, slo, shi);
    }

    for (int off = 32; off; off >>= 1) local += __shfl_down(local, off);
    __shared__ double sw[4];
    int wave = t >> 6, lane = t & 63;
    if (lane == 0) sw[wave] = local;
    __syncthreads();
    if (t == 0) hom_part[pb] = sw[0] + sw[1] + sw[2] + sw[3];
}

// ---------------------------------------------------------------------------
// the single fused persistent kernel. NG=512 blocks (2/CU, 8 waves/CU).
// K-split x2 everywhere; raw partials, consumer combines.
// R8 BUG FIXED: Wout has 32 tiles (512x64, nbx=2) -> 64 blocks = 32 tiles
// x Ksplit2 (R8 ran 16 tiles x4 splits, leaving rows 256-511 poisoned).
// ---------------------------------------------------------------------------
__global__ __launch_bounds__(256) void fused_k(
    const float* __restrict__ batch, const float* __restrict__ target,
    const float* __restrict__ W1, const float* __restrict__ b1,
    const float* __restrict__ W2, const float* __restrict__ b2,
    const float* __restrict__ W3, const float* __restrict__ b3,
    const float* __restrict__ Wout, const float* __restrict__ bout,
    const float* __restrict__ deaths, float* __restrict__ out,
    double* __restrict__ hA0, double* __restrict__ hA1,
    double* __restrict__ hB0, double* __restrict__ hB1,
    double* __restrict__ yvp,
    double* __restrict__ hom_part, double* __restrict__ t_part,
    double* __restrict__ c_part, unsigned* __restrict__ cnt) {
    const int bid = blockIdx.x;
    const int t   = threadIdx.x;

    __shared__ double As[2][16][33];
    __shared__ double Ws[2][16][33];
    __shared__ double slo[NSORT], shi[NSORT];
    __shared__ double rowsA[32 * RSTR], rowsB[32 * RSTR];
    double* sd = rowsA;                       // sort scratch alias

    const int tile = bid & 255;
    const int sp   = bid >> 8;                // K-split half (0/1)

    // P0: layer1 partials  hA{sp} = batch[:, sp*128:(sp+1)*128] @ W1[...]
    gemm_split<float, false>(batch, (const float*)nullptr, nullptr, W1,
                             sp ? hA1 : hA0, H_, IN_, sp * 128, 128, tile, t, As, Ws);
    gbar(&cnt[0], NG, true);
    // P1: layer2 partials; A = relu(hA0+hA1+b1)
    gemm_split<double, true>(hA0, hA1, b1, W2,
                             sp ? hB1 : hB0, H_, H_, sp * 256, 256, tile, t, As, Ws);
    gbar(&cnt[1], NG, true);
    // P2: layer3 partials; A = relu(hB0+hB1+b2)
    gemm_split<double, true>(hB0, hB1, b2, W3,
                             sp ? hA1 : hA0, H_, H_, sp * 256, 256, tile, t, As, Ws);
    gbar(&cnt[2], NG, true);

    // P3: Wout on 64 blocks = 32 tiles x Ksplit2; everyone else sorts
    if (bid < 64) {
        gemm_split<double, true>(hA0, hA1, b3, Wout,
                                 yvp + (size_t)(bid >> 5) * YSZ, OUT_, H_,
                                 (bid >> 5) * 256, 256, bid & 31, t, As, Ws);
    } else {
        sort_windows(deaths, sd, slo, shi, t);
    }
    gbar(&cnt[3], NG, true);

    // P4: tiled pdist on blocks 64..199 (windows sorted in P3); mc on 0..63
    if (bid >= 64 && bid < 64 + NTP)
        pdist_dev(yvp, bout, hom_part, bid - 64, t, rowsA, rowsB, slo, shi);
    if (bid < 64)
        mc_dev(target, yvp, bout, t_part, c_part, bid, t);

    // P5: block 0 reduces all partials
    gbar(&cnt[4], NG, bid == 0);
    if (bid == 0) {
        double h  = (t < NTP) ? __hip_atomic_load(&hom_part[t], __ATOMIC_RELAXED,
                                                  __HIP_MEMORY_SCOPE_AGENT) : 0.0;
        double tp = 0.0, cp = 0.0;
        if (t < OUT_) {
            tp = __hip_atomic_load(&t_part[t], __ATOMIC_RELAXED,
                                   __HIP_MEMORY_SCOPE_AGENT);
            cp = __hip_atomic_load(&c_part[t], __ATOMIC_RELAXED,
                                   __HIP_MEMORY_SCOPE_AGENT);
        }
        for (int off = 32; off; off >>= 1) {
            h  += __shfl_down(h,  off);
            tp += __shfl_down(tp, off);
            cp += __shfl_down(cp, off);
        }
        __shared__ double sh[4], stp[4], scp[4];
        int wave = t >> 6, lane = t & 63;
        if (lane == 0) { sh[wave] = h; stp[wave] = tp; scp[wave] = cp; }
        __syncthreads();
        if (t == 0) {
            double hs = sh[0]  + sh[1]  + sh[2]  + sh[3];
            double ts = stp[0] + stp[1] + stp[2] + stp[3];
            double cs = scp[0] + scp[1] + scp[2] + scp[3];
            out[0] = (float)(ts / (double)(B_ * OUT_) + hs + 0.01 * cs);
        }
    }
}

extern "C" void kernel_launch(void* const* d_in, const int* in_sizes, int n_in,
                              void* d_out, int out_size, void* d_ws, size_t ws_size,
                              hipStream_t stream) {
    const float* batch  = (const float*)d_in[0];
    const float* target = (const float*)d_in[1];
    const float* W1     = (const float*)d_in[2];
    const float* b1     = (const float*)d_in[3];
    const float* W2     = (const float*)d_in[4];
    const float* b2     = (const float*)d_in[5];
    const float* W3     = (const float*)d_in[6];
    const float* b3     = (const float*)d_in[7];
    const float* Wout   = (const float*)d_in[8];
    const float* bout   = (const float*)d_in[9];
    const float* deaths = (const float*)d_in[10];
    float* out = (float*)d_out;

    double* hA0      = (double*)d_ws;              // 512*512 each
    double* hA1      = hA0 + (size_t)B_ * H_;
    double* hB0      = hA1 + (size_t)B_ * H_;
    double* hB1      = hB0 + (size_t)B_ * H_;
    double* yvp      = hB1 + (size_t)B_ * H_;      // 2 partials x 512*64
    double* hom_part = yvp + 2 * (size_t)YSZ;      // 136
    double* t_part   = hom_part + NTP;             // 64
    double* c_part   = t_part + OUT_;              // 64
    unsigned* cnt    = (unsigned*)(c_part + OUT_); // 8 uints (5 used)

    hipMemsetAsync(cnt, 0, 8 * sizeof(unsigned), stream);

    fused_k<<<dim3(NG), dim3(256), 0, stream>>>(
        batch, target, W1, b1, W2, b2, W3, b3, Wout, bout, deaths, out,
        hA0, hA1, hB0, hB1, yvp, hom_part, t_part, c_part, cnt);
}

// Round 10
// 176.099 us; speedup vs baseline: 1.5333x; 1.5333x over previous
//
#include <hip/hip_runtime.h>

#define B_    512
#define IN_   256
#define H_    512
#define OUT_  64
#define NDEATH (B_ - 1)
#define NSORT  512          // NDEATH padded to pow2 for bitonic sort / bsearch
#define RTOL_ 1e-6
#define ATOL_ 1e-8
#define NBLK  256
#define KT    32            // K-tile (R10: was 16) -> 16 iters for K=512

typedef __attribute__((ext_vector_type(4))) double d4_t;

// ---------------------------------------------------------------------------
// software grid barrier (single-use counter): release add, relaxed spin,
// one acquire on exit. (R6-verified)
// ---------------------------------------------------------------------------
__device__ __forceinline__ void gbar(unsigned* cnt, unsigned nb, bool wait) {
    __syncthreads();
    if (threadIdx.x == 0) {
        __hip_atomic_fetch_add(cnt, 1u, __ATOMIC_RELEASE,
                               __HIP_MEMORY_SCOPE_AGENT);
        if (wait) {
            while (__hip_atomic_load(cnt, __ATOMIC_RELAXED,
                                     __HIP_MEMORY_SCOPE_AGENT) < nb)
                __builtin_amdgcn_s_sleep(2);
            (void)__hip_atomic_load(cnt, __ATOMIC_ACQUIRE,
                                    __HIP_MEMORY_SCOPE_AGENT);
        }
    }
    __syncthreads();
}

// ---------------------------------------------------------------------------
// per-block: bitonic-sort deaths into LDS, emit sorted tolerance windows.
// 256 threads, 512 elements. (verified R5-R9)
// ---------------------------------------------------------------------------
__device__ void sort_windows(const float* __restrict__ deaths,
                             double* sd, double* slo, double* shi, int t) {
    int i1 = t + 256;
    sd[t]  = (t  < NDEATH) ? (double)deaths[t]  : 1e300;
    sd[i1] = (i1 < NDEATH) ? (double)deaths[i1] : 1e300;
    __syncthreads();
    for (int k = 2; k <= NSORT; k <<= 1) {
        for (int j = k >> 1; j > 0; j >>= 1) {
            int l = ((t & ~(j - 1)) << 1) | (t & (j - 1));   // pair (l, l+j)
            int p = l + j;
            bool up = ((l & k) == 0);
            double a = sd[l], b = sd[p];
            if ((a > b) == up) { sd[l] = b; sd[p] = a; }
            __syncthreads();
        }
    }
    for (int i = t; i < NSORT; i += 256) {
        double d = sd[i];
        double w = ATOL_ + RTOL_ * fabs(d);
        slo[i] = d - w;
        shi[i] = d + w;
    }
    __syncthreads();
}

// ---------------------------------------------------------------------------
// f64 MFMA GEMM phase: C[512,N] = act(A[512,K] @ W[K,N] + bias[N]).
// R10: Kt=32 (16 iters at K=512) + DEPTH-2 register prefetch: tile kt+2 is
// issued while computing kt (~2 compute sections of latency cover, vs <1
// before). Accumulation order over k unchanged (quads ascending) -> C is
// bit-identical to R6. 32x32 tile, 4 waves x one v_mfma_f64_16x16x4_f64.
// ---------------------------------------------------------------------------
template <typename TIN, bool RELU>
__device__ void gemm_dev(const TIN* __restrict__ A, const float* __restrict__ W,
                         const float* __restrict__ bias, double* __restrict__ C,
                         int N, int K, int bid, int t,
                         double (&As)[2][KT][33], double (&Ws)[2][KT][33]) {
    const int lane = t & 63;
    const int wave = t >> 6;
    const int wm   = wave & 1, wn = wave >> 1;
    const int nbx  = N >> 5;
    const int row0 = (bid / nbx) << 5;
    const int col0 = (bid % nbx) << 5;

    const int akk = t & 31;          // k within A tile
    const int amm = t >> 5;          // base row (rows amm+8p, p=0..3)
    const int wnn = t & 31;          // col within W tile
    const int wkk = t >> 5;          // base k (k-rows wkk+8p)
    const int nkt = K >> 5;

    TIN   ar[2][4];
    float wr[2][4];

    auto load_to = [&](int rs, int kt) {
        const int k0 = kt << 5;
        #pragma unroll
        for (int p = 0; p < 4; ++p) {
            ar[rs][p] = A[(size_t)(row0 + amm + 8 * p) * K + k0 + akk];
            wr[rs][p] = W[(size_t)(k0 + wkk + 8 * p) * N + col0 + wnn];
        }
    };
    auto stage = [&](int rs, int buf) {
        #pragma unroll
        for (int p = 0; p < 4; ++p) {
            As[buf][akk][amm + 8 * p] = (double)ar[rs][p];
            Ws[buf][wkk + 8 * p][wnn] = (double)wr[rs][p];
        }
    };

    load_to(0, 0);
    if (nkt > 1) load_to(1, 1);
    stage(0, 0);
    __syncthreads();

    d4_t c4 = {0.0, 0.0, 0.0, 0.0};
    const int mrow = wm * 16 + (lane & 15);
    const int ncol = wn * 16 + (lane & 15);
    const int kq   = lane >> 4;

    for (int kt = 0; kt < nkt; ++kt) {
        const int cur = kt & 1;
        if (kt + 2 < nkt) load_to(cur, kt + 2);   // depth-2 prefetch
        #pragma unroll
        for (int ks = 0; ks < KT / 4; ++ks) {
            double av = As[cur][ks * 4 + kq][mrow];
            double bv = Ws[cur][ks * 4 + kq][ncol];
            c4 = __builtin_amdgcn_mfma_f64_16x16x4f64(av, bv, c4, 0, 0, 0);
        }
        __syncthreads();                          // all reads of LDS done
        if (kt + 1 < nkt) stage(cur ^ 1, cur ^ 1);
        __syncthreads();                          // next buffer filled
    }

    #pragma unroll
    for (int r = 0; r < 4; ++r) {
        int row = row0 + wm * 16 + (lane >> 4) * 4 + r;
        int col = col0 + wn * 16 + (lane & 15);
        double v = c4[r] + (double)bias[col];
        if (RELU) v = v > 0.0 ? v : 0.0;
        C[(size_t)row * N + col] = v;
    }
}

// ---------------------------------------------------------------------------
// column c: mean + target-MSE partial + compactness partial -> global slots
// ---------------------------------------------------------------------------
__device__ void mc_dev(const float* __restrict__ target,
                       const double* __restrict__ y,
                       double* __restrict__ t_part, double* __restrict__ c_part,
                       int c, int t) {
    const int wave = t >> 6, lane = t & 63;
    double v0 = y[(size_t)t * OUT_ + c];
    double v1 = y[(size_t)(t + 256) * OUT_ + c];
    double s = v0 + v1;
    for (int off = 32; off; off >>= 1) s += __shfl_down(s, off);
    __shared__ double swm[4];
    __shared__ double smean;
    if (lane == 0) swm[wave] = s;
    __syncthreads();
    if (t == 0) smean = (swm[0] + swm[1] + swm[2] + swm[3]) / (double)B_;
    __syncthreads();
    double m = smean;
    double d0 = (double)target[(size_t)t * OUT_ + c] - v0;
    double d1 = (double)target[(size_t)(t + 256) * OUT_ + c] - v1;
    double t_s = d0 * d0 + d1 * d1;
    double c_s = fabs(v0 - m) + fabs(v1 - m);
    for (int off = 32; off; off >>= 1) {
        t_s += __shfl_down(t_s, off);
        c_s += __shfl_down(c_s, off);
    }
    __shared__ double st[4], sc[4];
    if (lane == 0) { st[wave] = t_s; sc[wave] = c_s; }
    __syncthreads();
    if (t == 0) {
        t_part[c] = st[0] + st[1] + st[2] + st[3];
        c_part[c] = sc[0] + sc[1] + sc[2] + sc[3];
    }
}

// ---------------------------------------------------------------------------
// pdist + sorted-window match (R6 version). Block b: rows b and 510-b
// (512 pairs each, balanced). Match: lo/hi increasing => pd in any window
// <=> hi[ub-1] >= pd, ub from 9-step bsearch.
// ---------------------------------------------------------------------------
__device__ __forceinline__ double pair_val(const double* __restrict__ yrow_s,
                                           const double* __restrict__ yj,
                                           const double* __restrict__ slo,
                                           const double* __restrict__ shi) {
    double s = 0.0;
    #pragma unroll
    for (int d = 0; d < OUT_; d += 2) {
        double2 v = *(const double2*)(yj + d);
        double d0 = yrow_s[d]     - v.x;
        double d1 = yrow_s[d + 1] - v.y;
        s = fma(d0, d0, s);
        s = fma(d1, d1, s);
    }
    double pd = sqrt(s);
    int pos = 0;
    #pragma unroll
    for (int step = NSORT / 2; step; step >>= 1) {
        if (slo[pos + step - 1] <= pd) pos += step;
    }
    bool m = (pos > 0) && (shi[pos - 1] >= pd);
    return m ? pd : 0.0;
}

__device__ void pdist_dev(const double* __restrict__ y,
                          double* __restrict__ hom_part, int bid, int t,
                          double* yA, double* yB,
                          const double* slo, const double* shi) {
    const int iA = bid;
    const int iB = 510 - bid;     // == iA when bid == 255
    if (t < OUT_)            yA[t]        = y[(size_t)iA * OUT_ + t];
    else if (t < 2 * OUT_)   yB[t - OUT_] = y[(size_t)iB * OUT_ + (t - OUT_)];
    __syncthreads();

    double local = 0.0;
    for (int j = iA + 1 + t; j < B_; j += 256)
        local += pair_val(yA, y + (size_t)j * OUT_, slo, shi);
    if (iB != iA)
        for (int j = iB + 1 + t; j < B_; j += 256)
            local += pair_val(yB, y + (size_t)j * OUT_, slo, shi);

    for (int off = 32; off; off >>= 1) local += __shfl_down(local, off);
    __shared__ double sw[4];
    int wave = t >> 6, lane = t & 63;
    if (lane == 0) sw[wave] = local;
    __syncthreads();
    if (t == 0) hom_part[bid] = sw[0] + sw[1] + sw[2] + sw[3];
}

// ---------------------------------------------------------------------------
// the single fused persistent kernel (plain launch + software grid barriers)
// ---------------------------------------------------------------------------
__global__ __launch_bounds__(256) void fused_k(
    const float* __restrict__ batch, const float* __restrict__ target,
    const float* __restrict__ W1, const float* __restrict__ b1,
    const float* __restrict__ W2, const float* __restrict__ b2,
    const float* __restrict__ W3, const float* __restrict__ b3,
    const float* __restrict__ Wout, const float* __restrict__ bout,
    const float* __restrict__ deaths, float* __restrict__ out,
    double* __restrict__ hA, double* __restrict__ hB,
    double* __restrict__ yv,
    double* __restrict__ hom_part, double* __restrict__ t_part,
    double* __restrict__ c_part, unsigned* __restrict__ cnt) {
    const int bid = blockIdx.x;
    const int t   = threadIdx.x;

    __shared__ double As[2][KT][33];
    __shared__ double Ws[2][KT][33];
    __shared__ double slo[NSORT], shi[NSORT];
    __shared__ double yA[OUT_], yB[OUT_];
    double* sd = &As[0][0][0];                // sort scratch alias (512 dbl)

    // P0..P2: the three 512x512 GEMMs on all 256 blocks
    gemm_dev<float,  true>(batch, W1, b1, hA, H_, IN_, bid, t, As, Ws);
    gbar(&cnt[0], NBLK, true);
    gemm_dev<double, true>(hA, W2, b2, hB, H_, H_, bid, t, As, Ws);
    gbar(&cnt[1], NBLK, true);
    gemm_dev<double, true>(hB, W3, b3, hA, H_, H_, bid, t, As, Ws);
    gbar(&cnt[2], NBLK, true);

    // P3: Wout GEMM on blocks 0..31 (32 tiles, full K); others sort windows
    if (bid < 32) gemm_dev<double, false>(hA, Wout, bout, yv, OUT_, H_, bid, t, As, Ws);
    else          sort_windows(deaths, sd, slo, shi, t);
    gbar(&cnt[3], NBLK, true);
    if (bid < 32) sort_windows(deaths, sd, slo, shi, t);

    // P4: pdist on all 256 blocks; mean/MSE/compactness on blocks 0..63
    pdist_dev(yv, hom_part, bid, t, yA, yB, slo, shi);
    if (bid < OUT_) mc_dev(target, yv, t_part, c_part, bid, t);

    // P5: block 0 reduces all partials
    gbar(&cnt[4], NBLK, bid == 0);
    if (bid == 0) {
        double h  = __hip_atomic_load(&hom_part[t], __ATOMIC_RELAXED,
                                      __HIP_MEMORY_SCOPE_AGENT);
        double tp = 0.0, cp = 0.0;
        if (t < OUT_) {
            tp = __hip_atomic_load(&t_part[t], __ATOMIC_RELAXED,
                                   __HIP_MEMORY_SCOPE_AGENT);
            cp = __hip_atomic_load(&c_part[t], __ATOMIC_RELAXED,
                                   __HIP_MEMORY_SCOPE_AGENT);
        }
        for (int off = 32; off; off >>= 1) {
            h  += __shfl_down(h,  off);
            tp += __shfl_down(tp, off);
            cp += __shfl_down(cp, off);
        }
        __shared__ double sh[4], stp[4], scp[4];
        int wave = t >> 6, lane = t & 63;
        if (lane == 0) { sh[wave] = h; stp[wave] = tp; scp[wave] = cp; }
        __syncthreads();
        if (t == 0) {
            double hs = sh[0]  + sh[1]  + sh[2]  + sh[3];
            double ts = stp[0] + stp[1] + stp[2] + stp[3];
            double cs = scp[0] + scp[1] + scp[2] + scp[3];
            out[0] = (float)(ts / (double)(B_ * OUT_) + hs + 0.01 * cs);
        }
    }
}

extern "C" void kernel_launch(void* const* d_in, const int* in_sizes, int n_in,
                              void* d_out, int out_size, void* d_ws, size_t ws_size,
                              hipStream_t stream) {
    const float* batch  = (const float*)d_in[0];
    const float* target = (const float*)d_in[1];
    const float* W1     = (const float*)d_in[2];
    const float* b1     = (const float*)d_in[3];
    const float* W2     = (const float*)d_in[4];
    const float* b2     = (const float*)d_in[5];
    const float* W3     = (const float*)d_in[6];
    const float* b3     = (const float*)d_in[7];
    const float* Wout   = (const float*)d_in[8];
    const float* bout   = (const float*)d_in[9];
    const float* deaths = (const float*)d_in[10];
    float* out = (float*)d_out;

    double* hA       = (double*)d_ws;              // 512*512
    double* hB       = hA + (size_t)B_ * H_;       // 512*512
    double* yv       = hB + (size_t)B_ * H_;       // 512*64
    double* hom_part = yv + (size_t)B_ * OUT_;     // 256
    double* t_part   = hom_part + NBLK;            // 64
    double* c_part   = t_part + OUT_;              // 64
    unsigned* cnt    = (unsigned*)(c_part + OUT_); // 8 uints (5 used)

    hipMemsetAsync(cnt, 0, 8 * sizeof(unsigned), stream);

    fused_k<<<dim3(NBLK), dim3(256), 0, stream>>>(
        batch, target, W1, b1, W2, b2, W3, b3, Wout, bout, deaths, out,
        hA, hB, yv, hom_part, t_part, c_part, cnt);
}

// Round 11
// 142.296 us; speedup vs baseline: 1.8976x; 1.2375x over previous
//
#include <hip/hip_runtime.h>

#define B_    512
#define IN_   256
#define H_    512
#define OUT_  64
#define NDEATH (B_ - 1)
#define NSORT  512          // NDEATH padded to pow2 for bitonic sort / bsearch
#define RTOL_ 1e-6
#define ATOL_ 1e-8
#define NBLK  256
#define KT    32            // K-tile -> 16 iters for K=512 (R10-verified)

typedef __attribute__((ext_vector_type(4))) double d4_t;

// agent-visible store: relaxed atomic, bypasses L2 -> lands at coherence
// point (L3). No dirty L2 lines => barriers need NO wbl2/inv fences.
__device__ __forceinline__ void ast(double* p, double v) {
    __hip_atomic_store(p, v, __ATOMIC_RELAXED, __HIP_MEMORY_SCOPE_AGENT);
}

// ---------------------------------------------------------------------------
// software grid barrier, FENCELESS (R11): __syncthreads drains vmcnt (all
// our atomic stores are at L3 by then); relaxed add + relaxed spin. No
// acquire/release => no per-block buffer_wbl2/buffer_inv L2 tag-walks
// (R10 theory: 256 serialized walks/barrier ~= 15us each, ~80us total).
// Reader safety: inter-phase buffers are written-once-then-read (hA/hB/hC
// chain), so normal cached reads can never hit a stale line in-kernel;
// the dispatch-start implicit acquire cleans cross-call leftovers.
// ---------------------------------------------------------------------------
__device__ __forceinline__ void gbar(unsigned* cnt, unsigned nb, bool wait) {
    __syncthreads();
    if (threadIdx.x == 0) {
        __hip_atomic_fetch_add(cnt, 1u, __ATOMIC_RELAXED,
                               __HIP_MEMORY_SCOPE_AGENT);
        if (wait) {
            while (__hip_atomic_load(cnt, __ATOMIC_RELAXED,
                                     __HIP_MEMORY_SCOPE_AGENT) < nb)
                __builtin_amdgcn_s_sleep(2);
        }
    }
    __syncthreads();
}

// ---------------------------------------------------------------------------
// per-block: bitonic-sort deaths into LDS, emit sorted tolerance windows.
// 256 threads, 512 elements. (verified R5-R10)
// ---------------------------------------------------------------------------
__device__ void sort_windows(const float* __restrict__ deaths,
                             double* sd, double* slo, double* shi, int t) {
    int i1 = t + 256;
    sd[t]  = (t  < NDEATH) ? (double)deaths[t]  : 1e300;
    sd[i1] = (i1 < NDEATH) ? (double)deaths[i1] : 1e300;
    __syncthreads();
    for (int k = 2; k <= NSORT; k <<= 1) {
        for (int j = k >> 1; j > 0; j >>= 1) {
            int l = ((t & ~(j - 1)) << 1) | (t & (j - 1));   // pair (l, l+j)
            int p = l + j;
            bool up = ((l & k) == 0);
            double a = sd[l], b = sd[p];
            if ((a > b) == up) { sd[l] = b; sd[p] = a; }
            __syncthreads();
        }
    }
    for (int i = t; i < NSORT; i += 256) {
        double d = sd[i];
        double w = ATOL_ + RTOL_ * fabs(d);
        slo[i] = d - w;
        shi[i] = d + w;
    }
    __syncthreads();
}

// ---------------------------------------------------------------------------
// f64 MFMA GEMM phase: C[512,N] = act(A[512,K] @ W[K,N] + bias[N]).
// Kt=32 (16 iters) + depth-2 register prefetch (R10-verified). C written
// via agent atomic stores (R11). Accumulation order unchanged since R6 ->
// bit-identical C values.
// ---------------------------------------------------------------------------
template <typename TIN, bool RELU>
__device__ void gemm_dev(const TIN* __restrict__ A, const float* __restrict__ W,
                         const float* __restrict__ bias, double* __restrict__ C,
                         int N, int K, int bid, int t,
                         double (&As)[2][KT][33], double (&Ws)[2][KT][33]) {
    const int lane = t & 63;
    const int wave = t >> 6;
    const int wm   = wave & 1, wn = wave >> 1;
    const int nbx  = N >> 5;
    const int row0 = (bid / nbx) << 5;
    const int col0 = (bid % nbx) << 5;

    const int akk = t & 31;          // k within A tile
    const int amm = t >> 5;          // base row (rows amm+8p, p=0..3)
    const int wnn = t & 31;          // col within W tile
    const int wkk = t >> 5;          // base k (k-rows wkk+8p)
    const int nkt = K >> 5;

    TIN   ar[2][4];
    float wr[2][4];

    auto load_to = [&](int rs, int kt) {
        const int k0 = kt << 5;
        #pragma unroll
        for (int p = 0; p < 4; ++p) {
            ar[rs][p] = A[(size_t)(row0 + amm + 8 * p) * K + k0 + akk];
            wr[rs][p] = W[(size_t)(k0 + wkk + 8 * p) * N + col0 + wnn];
        }
    };
    auto stage = [&](int rs, int buf) {
        #pragma unroll
        for (int p = 0; p < 4; ++p) {
            As[buf][akk][amm + 8 * p] = (double)ar[rs][p];
            Ws[buf][wkk + 8 * p][wnn] = (double)wr[rs][p];
        }
    };

    load_to(0, 0);
    if (nkt > 1) load_to(1, 1);
    stage(0, 0);
    __syncthreads();

    d4_t c4 = {0.0, 0.0, 0.0, 0.0};
    const int mrow = wm * 16 + (lane & 15);
    const int ncol = wn * 16 + (lane & 15);
    const int kq   = lane >> 4;

    for (int kt = 0; kt < nkt; ++kt) {
        const int cur = kt & 1;
        if (kt + 2 < nkt) load_to(cur, kt + 2);   // depth-2 prefetch
        #pragma unroll
        for (int ks = 0; ks < KT / 4; ++ks) {
            double av = As[cur][ks * 4 + kq][mrow];
            double bv = Ws[cur][ks * 4 + kq][ncol];
            c4 = __builtin_amdgcn_mfma_f64_16x16x4f64(av, bv, c4, 0, 0, 0);
        }
        __syncthreads();                          // all reads of LDS done
        if (kt + 1 < nkt) stage(cur ^ 1, cur ^ 1);
        __syncthreads();                          // next buffer filled
    }

    #pragma unroll
    for (int r = 0; r < 4; ++r) {
        int row = row0 + wm * 16 + (lane >> 4) * 4 + r;
        int col = col0 + wn * 16 + (lane & 15);
        double v = c4[r] + (double)bias[col];
        if (RELU) v = v > 0.0 ? v : 0.0;
        ast(&C[(size_t)row * N + col], v);
    }
}

// ---------------------------------------------------------------------------
// column c: mean + target-MSE partial + compactness partial -> global slots
// ---------------------------------------------------------------------------
__device__ void mc_dev(const float* __restrict__ target,
                       const double* __restrict__ y,
                       double* __restrict__ t_part, double* __restrict__ c_part,
                       int c, int t) {
    const int wave = t >> 6, lane = t & 63;
    double v0 = y[(size_t)t * OUT_ + c];
    double v1 = y[(size_t)(t + 256) * OUT_ + c];
    double s = v0 + v1;
    for (int off = 32; off; off >>= 1) s += __shfl_down(s, off);
    __shared__ double swm[4];
    __shared__ double smean;
    if (lane == 0) swm[wave] = s;
    __syncthreads();
    if (t == 0) smean = (swm[0] + swm[1] + swm[2] + swm[3]) / (double)B_;
    __syncthreads();
    double m = smean;
    double d0 = (double)target[(size_t)t * OUT_ + c] - v0;
    double d1 = (double)target[(size_t)(t + 256) * OUT_ + c] - v1;
    double t_s = d0 * d0 + d1 * d1;
    double c_s = fabs(v0 - m) + fabs(v1 - m);
    for (int off = 32; off; off >>= 1) {
        t_s += __shfl_down(t_s, off);
        c_s += __shfl_down(c_s, off);
    }
    __shared__ double st[4], sc[4];
    if (lane == 0) { st[wave] = t_s; sc[wave] = c_s; }
    __syncthreads();
    if (t == 0) {
        ast(&t_part[c], st[0] + st[1] + st[2] + st[3]);
        ast(&c_part[c], sc[0] + sc[1] + sc[2] + sc[3]);
    }
}

// ---------------------------------------------------------------------------
// pdist + sorted-window match. Block b: rows b and 510-b (512 pairs each,
// balanced). Match: lo/hi increasing => pd in any window <=> hi[ub-1] >= pd.
// ---------------------------------------------------------------------------
__device__ __forceinline__ double pair_val(const double* __restrict__ yrow_s,
                                           const double* __restrict__ yj,
                                           const double* __restrict__ slo,
                                           const double* __restrict__ shi) {
    double s = 0.0;
    #pragma unroll
    for (int d = 0; d < OUT_; d += 2) {
        double2 v = *(const double2*)(yj + d);
        double d0 = yrow_s[d]     - v.x;
        double d1 = yrow_s[d + 1] - v.y;
        s = fma(d0, d0, s);
        s = fma(d1, d1, s);
    }
    double pd = sqrt(s);
    int pos = 0;
    #pragma unroll
    for (int step = NSORT / 2; step; step >>= 1) {
        if (slo[pos + step - 1] <= pd) pos += step;
    }
    bool m = (pos > 0) && (shi[pos - 1] >= pd);
    return m ? pd : 0.0;
}

__device__ void pdist_dev(const double* __restrict__ y,
                          double* __restrict__ hom_part, int bid, int t,
                          double* yA, double* yB,
                          const double* slo, const double* shi) {
    const int iA = bid;
    const int iB = 510 - bid;     // == iA when bid == 255
    if (t < OUT_)            yA[t]        = y[(size_t)iA * OUT_ + t];
    else if (t < 2 * OUT_)   yB[t - OUT_] = y[(size_t)iB * OUT_ + (t - OUT_)];
    __syncthreads();

    double local = 0.0;
    for (int j = iA + 1 + t; j < B_; j += 256)
        local += pair_val(yA, y + (size_t)j * OUT_, slo, shi);
    if (iB != iA)
        for (int j = iB + 1 + t; j < B_; j += 256)
            local += pair_val(yB, y + (size_t)j * OUT_, slo, shi);

    for (int off = 32; off; off >>= 1) local += __shfl_down(local, off);
    __shared__ double sw[4];
    int wave = t >> 6, lane = t & 63;
    if (lane == 0) sw[wave] = local;
    __syncthreads();
    if (t == 0) ast(&hom_part[bid], sw[0] + sw[1] + sw[2] + sw[3]);
}

// ---------------------------------------------------------------------------
// the single fused persistent kernel (fenceless barriers, write-once buffer
// chain hA -> hB -> hC -> yv).
// ---------------------------------------------------------------------------
__global__ __launch_bounds__(256) void fused_k(
    const float* __restrict__ batch, const float* __restrict__ target,
    const float* __restrict__ W1, const float* __restrict__ b1,
    const float* __restrict__ W2, const float* __restrict__ b2,
    const float* __restrict__ W3, const float* __restrict__ b3,
    const float* __restrict__ Wout, const float* __restrict__ bout,
    const float* __restrict__ deaths, float* __restrict__ out,
    double* __restrict__ hA, double* __restrict__ hB,
    double* __restrict__ hC, double* __restrict__ yv,
    double* __restrict__ hom_part, double* __restrict__ t_part,
    double* __restrict__ c_part, unsigned* __restrict__ cnt) {
    const int bid = blockIdx.x;
    const int t   = threadIdx.x;

    __shared__ double As[2][KT][33];
    __shared__ double Ws[2][KT][33];
    __shared__ double slo[NSORT], shi[NSORT];
    __shared__ double yA[OUT_], yB[OUT_];
    double* sd = &As[0][0][0];                // sort scratch alias (512 dbl)

    // P0..P2: the three 512x512 GEMMs on all 256 blocks (write-once chain)
    gemm_dev<float,  true>(batch, W1, b1, hA, H_, IN_, bid, t, As, Ws);
    gbar(&cnt[0], NBLK, true);
    gemm_dev<double, true>(hA, W2, b2, hB, H_, H_, bid, t, As, Ws);
    gbar(&cnt[1], NBLK, true);
    gemm_dev<double, true>(hB, W3, b3, hC, H_, H_, bid, t, As, Ws);
    gbar(&cnt[2], NBLK, true);

    // P3: Wout GEMM on blocks 0..31 (32 tiles, full K); others sort windows
    if (bid < 32) gemm_dev<double, false>(hC, Wout, bout, yv, OUT_, H_, bid, t, As, Ws);
    else          sort_windows(deaths, sd, slo, shi, t);
    gbar(&cnt[3], NBLK, true);
    if (bid < 32) sort_windows(deaths, sd, slo, shi, t);

    // P4: pdist on all 256 blocks; mean/MSE/compactness on blocks 0..63
    pdist_dev(yv, hom_part, bid, t, yA, yB, slo, shi);
    if (bid < OUT_) mc_dev(target, yv, t_part, c_part, bid, t);

    // P5: block 0 reduces all partials
    gbar(&cnt[4], NBLK, bid == 0);
    if (bid == 0) {
        double h  = __hip_atomic_load(&hom_part[t], __ATOMIC_RELAXED,
                                      __HIP_MEMORY_SCOPE_AGENT);
        double tp = 0.0, cp = 0.0;
        if (t < OUT_) {
            tp = __hip_atomic_load(&t_part[t], __ATOMIC_RELAXED,
                                   __HIP_MEMORY_SCOPE_AGENT);
            cp = __hip_atomic_load(&c_part[t], __ATOMIC_RELAXED,
                                   __HIP_MEMORY_SCOPE_AGENT);
        }
        for (int off = 32; off; off >>= 1) {
            h  += __shfl_down(h,  off);
            tp += __shfl_down(tp, off);
            cp += __shfl_down(cp, off);
        }
        __shared__ double sh[4], stp[4], scp[4];
        int wave = t >> 6, lane = t & 63;
        if (lane == 0) { sh[wave] = h; stp[wave] = tp; scp[wave] = cp; }
        __syncthreads();
        if (t == 0) {
            double hs = sh[0]  + sh[1]  + sh[2]  + sh[3];
            double ts = stp[0] + stp[1] + stp[2] + stp[3];
            double cs = scp[0] + scp[1] + scp[2] + scp[3];
            out[0] = (float)(ts / (double)(B_ * OUT_) + hs + 0.01 * cs);
        }
    }
}

extern "C" void kernel_launch(void* const* d_in, const int* in_sizes, int n_in,
                              void* d_out, int out_size, void* d_ws, size_t ws_size,
                              hipStream_t stream) {
    const float* batch  = (const float*)d_in[0];
    const float* target = (const float*)d_in[1];
    const float* W1     = (const float*)d_in[2];
    const float* b1     = (const float*)d_in[3];
    const float* W2     = (const float*)d_in[4];
    const float* b2     = (const float*)d_in[5];
    const float* W3     = (const float*)d_in[6];
    const float* b3     = (const float*)d_in[7];
    const float* Wout   = (const float*)d_in[8];
    const float* bout   = (const float*)d_in[9];
    const float* deaths = (const float*)d_in[10];
    float* out = (float*)d_out;

    double* hA       = (double*)d_ws;              // 512*512
    double* hB       = hA + (size_t)B_ * H_;       // 512*512
    double* hC       = hB + (size_t)B_ * H_;       // 512*512
    double* yv       = hC + (size_t)B_ * H_;       // 512*64
    double* hom_part = yv + (size_t)B_ * OUT_;     // 256
    double* t_part   = hom_part + NBLK;            // 64
    double* c_part   = t_part + OUT_;              // 64
    unsigned* cnt    = (unsigned*)(c_part + OUT_); // 8 uints (5 used)

    hipMemsetAsync(cnt, 0, 8 * sizeof(unsigned), stream);

    fused_k<<<dim3(NBLK), dim3(256), 0, stream>>>(
        batch, target, W1, b1, W2, b2, W3, b3, Wout, bout, deaths, out,
        hA, hB, hC, yv, hom_part, t_part, c_part, cnt);
}